// Round 1
// baseline (480.339 us; speedup 1.0000x reference)
//
#include <hip/hip_runtime.h>
#include <hip/hip_bf16.h>

// ---------- types ----------
typedef __bf16 bf16x8 __attribute__((ext_vector_type(8)));
typedef __bf16 bf16x4 __attribute__((ext_vector_type(4)));
typedef float  f32x4  __attribute__((ext_vector_type(4)));

typedef const __attribute__((address_space(1))) void* gptr_t;
typedef __attribute__((address_space(3))) void*       lptr_t;

#define NQ 2048
#define NK 2048
#define AD 1024
#define NH 16
#define HD 64
#define HC 1024   // NH*HD

// ---------- prep 1: fp32 -> bf16 for q_data / m_data ----------
__global__ __launch_bounds__(256) void prep_convert(
    const float* __restrict__ q_data, const float* __restrict__ m_data,
    __bf16* __restrict__ aq, __bf16* __restrict__ am) {
  const int NEL4 = NQ * AD / 4;  // 524288 float4 per matrix
  int gid = blockIdx.x * 256 + threadIdx.x;  // 0 .. 2*NEL4-1
  float4 v;
  __bf16* dst;
  if (gid < NEL4) { v = ((const float4*)q_data)[gid]; dst = aq + (size_t)gid * 4; }
  else            { v = ((const float4*)m_data)[gid - NEL4]; dst = am + (size_t)(gid - NEL4) * 4; }
  bf16x4 o;
  o[0] = (__bf16)v.x; o[1] = (__bf16)v.y; o[2] = (__bf16)v.z; o[3] = (__bf16)v.w;
  *(bf16x4*)dst = o;
}

// ---------- prep 2: weight [a][hc] fp32 -> [hc][a] bf16 (transpose) ----------
__global__ __launch_bounds__(256) void prep_transpose(
    const float* __restrict__ w0, const float* __restrict__ w1,
    const float* __restrict__ w2, const float* __restrict__ w3,
    __bf16* __restrict__ t0, __bf16* __restrict__ t1,
    __bf16* __restrict__ t2, __bf16* __restrict__ t3) {
  __shared__ float tile[64][65];  // +1 pad: conflict-free transposed reads
  int b = blockIdx.x;
  int wsel = b >> 8;        // 0..3 which weight
  int t = b & 255;          // 256 tiles of 64x64 over 1024x1024
  int a0 = (t >> 4) * 64, n0 = (t & 15) * 64;
  const float* W = (wsel == 0) ? w0 : (wsel == 1) ? w1 : (wsel == 2) ? w2 : w3;
  __bf16*      T = (wsel == 0) ? t0 : (wsel == 1) ? t1 : (wsel == 2) ? t2 : t3;
  int tx = threadIdx.x & 63, ty = threadIdx.x >> 6;  // ty 0..3
#pragma unroll
  for (int r = 0; r < 64; r += 4)
    tile[ty + r][tx] = W[(size_t)(a0 + ty + r) * HC + n0 + tx];
  __syncthreads();
#pragma unroll
  for (int r = 0; r < 64; r += 4)
    T[(size_t)(n0 + ty + r) * AD + a0 + tx] = (__bf16)tile[tx][ty + r];
}

// ---------- projection GEMM: C[m][n] = sum_k A[m][k] * Bt[n][k] ----------
// 128x128 tile, BK=32, 4 waves in 2x2, 4x4 16x16x32 MFMA per wave.
// mode 0: Q  = (Aq x Wq + qbias)*scale -> qb  [h][q][c] bf16
// mode 1: K  =  Am x Wk                -> kb  [h][k][c] bf16
// mode 2: Vt =  Wv x Am  (swapped ops) -> vt  [hc][kv]  bf16 (i.e. V^T)
// mode 3: G  = sigmoid(Aq x Wg)        -> gate[q][hc]   fp32
__global__ __launch_bounds__(256) void proj_gemm(
    const __bf16* __restrict__ Aq, const __bf16* __restrict__ Am,
    const __bf16* __restrict__ Wq, const __bf16* __restrict__ Wk,
    const __bf16* __restrict__ Wv, const __bf16* __restrict__ Wg,
    const float* __restrict__ qbias,
    __bf16* __restrict__ qb, __bf16* __restrict__ kb,
    __bf16* __restrict__ vt, float* __restrict__ gate) {
  __shared__ __bf16 As[128 * 32];
  __shared__ __bf16 Bs[128 * 32];
  int bx = blockIdx.x;
  int mode = bx >> 7, t = bx & 127;
  const __bf16 *A, *B;
  int bm, bn;
  if (mode == 2) {  // M=1024 (hc), N=2048 (kv)
    A = Wv; B = Am; bm = (t >> 4) << 7; bn = (t & 15) << 7;
  } else {          // M=2048, N=1024
    bm = (t >> 3) << 7; bn = (t & 7) << 7;
    A = (mode == 1) ? Am : Aq;
    B = (mode == 0) ? Wq : (mode == 1) ? Wk : Wg;
  }
  int lane = threadIdx.x & 63, wave = threadIdx.x >> 6;
  int quad = lane >> 4, l15 = lane & 15;
  int wm = (wave >> 1) << 6, wn = (wave & 1) << 6;
  int srow = lane >> 2, schunk = lane & 3;  // staging: 16 rows x 4 16B-chunks per instr

  f32x4 acc[4][4] = {};

  for (int k0 = 0; k0 < AD; k0 += 32) {
#pragma unroll
    for (int i = 0; i < 2; i++) {
      int inst = wave * 2 + i;
      int row = inst * 16 + srow;
      __builtin_amdgcn_global_load_lds(
          (gptr_t)((const char*)A + ((size_t)(bm + row) * AD + k0) * 2 + schunk * 16),
          (lptr_t)(As + inst * 512), 16, 0, 0);
      __builtin_amdgcn_global_load_lds(
          (gptr_t)((const char*)B + ((size_t)(bn + row) * AD + k0) * 2 + schunk * 16),
          (lptr_t)(Bs + inst * 512), 16, 0, 0);
    }
    __syncthreads();
    bf16x8 af[4], bfr[4];
#pragma unroll
    for (int i = 0; i < 4; i++) af[i]  = *(const bf16x8*)(As + (wm + i * 16 + l15) * 32 + quad * 8);
#pragma unroll
    for (int j = 0; j < 4; j++) bfr[j] = *(const bf16x8*)(Bs + (wn + j * 16 + l15) * 32 + quad * 8);
#pragma unroll
    for (int i = 0; i < 4; i++)
#pragma unroll
      for (int j = 0; j < 4; j++)
        acc[i][j] = __builtin_amdgcn_mfma_f32_16x16x32_bf16(af[i], bfr[j], acc[i][j], 0, 0, 0);
    __syncthreads();
  }

  // epilogue: C/D layout col = lane&15, row = quad*4 + reg
#pragma unroll
  for (int j = 0; j < 4; j++) {
    int n = bn + wn + j * 16 + l15;
    float qbb = (mode == 0) ? qbias[n] : 0.f;
#pragma unroll
    for (int i = 0; i < 4; i++) {
#pragma unroll
      for (int r = 0; r < 4; r++) {
        int m = bm + wm + i * 16 + quad * 4 + r;
        float v = acc[i][j][r];
        if (mode == 0) {
          int h = n >> 6, c = n & 63;
          qb[((size_t)h * NQ + m) * HD + c] = (__bf16)((v + qbb) * 0.125f);
        } else if (mode == 1) {
          int h = n >> 6, c = n & 63;
          kb[((size_t)h * NK + m) * HD + c] = (__bf16)v;
        } else if (mode == 2) {
          vt[(size_t)m * NK + n] = (__bf16)v;
        } else {
          gate[(size_t)m * HC + n] = 1.f / (1.f + __expf(-v));
        }
      }
    }
  }
}

// ---------- flash attention ----------
// block = (head h, 64 q rows), 4 waves x 16-row strips. No barriers.
__global__ __launch_bounds__(256) void attn(
    const __bf16* __restrict__ qb, const __bf16* __restrict__ kb,
    const __bf16* __restrict__ vt, const float* __restrict__ gate,
    const float* __restrict__ bias, float* __restrict__ out) {
  __shared__ __bf16 P_lds[4][16 * 68];  // per-wave strip, row stride 68 (conflict-tamed, 8B-aligned rows)
  int bx = blockIdx.x;
  int h = bx & 15, q0 = (bx >> 4) << 6;
  int lane = threadIdx.x & 63, wave = threadIdx.x >> 6;
  int quad = lane >> 4, l15 = lane & 15;
  int qrow = q0 + wave * 16;

  const __bf16* qh = qb + (size_t)h * NQ * HD;
  const __bf16* kh = kb + (size_t)h * NK * HD;
  const __bf16* vh = vt + (size_t)h * HD * NK;
  const float*  bh = bias + (size_t)h * NQ * NK;

  bf16x8 a_q[2];
#pragma unroll
  for (int kk = 0; kk < 2; kk++)
    a_q[kk] = *(const bf16x8*)(qh + (size_t)(qrow + l15) * HD + quad * 8 + kk * 32);

  float m_r[4], l_r[4];
  f32x4 acc_o[4] = {};
#pragma unroll
  for (int r = 0; r < 4; r++) { m_r[r] = -1e30f; l_r[r] = 0.f; }
  __bf16* pl = &P_lds[wave][0];

  for (int k0 = 0; k0 < NK; k0 += 64) {
    // bias tile directly into MFMA C operand (this is the HBM stream)
    f32x4 s[4];
#pragma unroll
    for (int jt = 0; jt < 4; jt++)
#pragma unroll
      for (int r = 0; r < 4; r++)
        s[jt][r] = bh[(size_t)(qrow + quad * 4 + r) * NK + k0 + jt * 16 + l15];

    bf16x8 b_k[4][2], b_v[4][2];
#pragma unroll
    for (int jt = 0; jt < 4; jt++)
#pragma unroll
      for (int kk = 0; kk < 2; kk++) {
        b_k[jt][kk] = *(const bf16x8*)(kh + (size_t)(k0 + jt * 16 + l15) * HD + quad * 8 + kk * 32);
        b_v[jt][kk] = *(const bf16x8*)(vh + (size_t)(jt * 16 + l15) * NK + k0 + quad * 8 + kk * 32);
      }

#pragma unroll
    for (int jt = 0; jt < 4; jt++)
#pragma unroll
      for (int kk = 0; kk < 2; kk++)
        s[jt] = __builtin_amdgcn_mfma_f32_16x16x32_bf16(a_q[kk], b_k[jt][kk], s[jt], 0, 0, 0);

    // online softmax on 4 rows/lane (row = quad*4+r, cols spread over 16 lanes x 4 jt)
    float p[4][4];
#pragma unroll
    for (int r = 0; r < 4; r++) {
      float mx = fmaxf(fmaxf(s[0][r], s[1][r]), fmaxf(s[2][r], s[3][r]));
#pragma unroll
      for (int off = 1; off < 16; off <<= 1) mx = fmaxf(mx, __shfl_xor(mx, off));
      float mn = fmaxf(m_r[r], mx);
      float alpha = __expf(m_r[r] - mn);
      m_r[r] = mn;
      float sum = 0.f;
#pragma unroll
      for (int jt = 0; jt < 4; jt++) {
        float pv = __expf(s[jt][r] - mn);
        p[jt][r] = pv;
        sum += pv;
      }
#pragma unroll
      for (int off = 1; off < 16; off <<= 1) sum += __shfl_xor(sum, off);
      l_r[r] = l_r[r] * alpha + sum;
#pragma unroll
      for (int jt = 0; jt < 4; jt++) acc_o[jt][r] *= alpha;
    }

    // P: C-layout -> A-layout via wave-private LDS (in-order wave, no barrier needed)
#pragma unroll
    for (int jt = 0; jt < 4; jt++)
#pragma unroll
      for (int r = 0; r < 4; r++)
        pl[(quad * 4 + r) * 68 + jt * 16 + l15] = (__bf16)p[jt][r];

    bf16x8 a_p[2];
#pragma unroll
    for (int kk = 0; kk < 2; kk++) {
      const __bf16* src = pl + l15 * 68 + quad * 8 + kk * 32;
      bf16x4 lo = *(const bf16x4*)src;
      bf16x4 hi = *(const bf16x4*)(src + 4);
      bf16x8 a;
#pragma unroll
      for (int j = 0; j < 4; j++) { a[j] = lo[j]; a[4 + j] = hi[j]; }
      a_p[kk] = a;
    }

#pragma unroll
    for (int jt = 0; jt < 4; jt++)
#pragma unroll
      for (int kk = 0; kk < 2; kk++)
        acc_o[jt] = __builtin_amdgcn_mfma_f32_16x16x32_bf16(a_p[kk], b_v[jt][kk], acc_o[jt], 0, 0, 0);
  }

  // epilogue: normalize, gate, store fp32 [q][h][d]
#pragma unroll
  for (int jt = 0; jt < 4; jt++)
#pragma unroll
    for (int r = 0; r < 4; r++) {
      int q = qrow + quad * 4 + r;
      int d = jt * 16 + l15;
      float g = gate[(size_t)q * HC + h * HD + d];
      out[((size_t)q * NH + h) * HD + d] = acc_o[jt][r] / l_r[r] * g;
    }
}

// ---------- launch ----------
extern "C" void kernel_launch(void* const* d_in, const int* in_sizes, int n_in,
                              void* d_out, int out_size, void* d_ws, size_t ws_size,
                              hipStream_t stream) {
  const float* q_data   = (const float*)d_in[0];
  const float* m_data   = (const float*)d_in[1];
  const float* bias     = (const float*)d_in[2];
  const float* query_w  = (const float*)d_in[3];
  const float* query_b  = (const float*)d_in[4];
  const float* key_w    = (const float*)d_in[5];
  const float* value_w  = (const float*)d_in[6];
  const float* gating_w = (const float*)d_in[7];
  float* out = (float*)d_out;

  char* ws = (char*)d_ws;
  __bf16* Aq   = (__bf16*)(ws);                       // 4 MB  [2048][1024]
  __bf16* Am   = (__bf16*)(ws + ((size_t)4 << 20));   // 4 MB
  __bf16* Wq   = (__bf16*)(ws + ((size_t)8 << 20));   // 2 MB  [hc][a]
  __bf16* Wk   = (__bf16*)(ws + ((size_t)10 << 20));  // 2 MB
  __bf16* Wv   = (__bf16*)(ws + ((size_t)12 << 20));  // 2 MB
  __bf16* Wg   = (__bf16*)(ws + ((size_t)14 << 20));  // 2 MB
  __bf16* qbuf = (__bf16*)(ws + ((size_t)16 << 20));  // 4 MB  [h][q][c]
  __bf16* kbuf = (__bf16*)(ws + ((size_t)20 << 20));  // 4 MB  [h][k][c]
  __bf16* vtb  = (__bf16*)(ws + ((size_t)24 << 20));  // 4 MB  [hc][kv]
  float*  gbuf = (float*)(ws + ((size_t)28 << 20));   // 8 MB  [q][hc]

  prep_convert<<<4096, 256, 0, stream>>>(q_data, m_data, Aq, Am);
  prep_transpose<<<1024, 256, 0, stream>>>(query_w, key_w, value_w, gating_w, Wq, Wk, Wv, Wg);
  proj_gemm<<<512, 256, 0, stream>>>(Aq, Am, Wq, Wk, Wv, Wg, query_b, qbuf, kbuf, vtb, gbuf);
  attn<<<512, 256, 0, stream>>>(qbuf, kbuf, vtb, gbuf, bias, out);
}